// Round 1
// baseline (558.838 us; speedup 1.0000x reference)
//
#include <hip/hip_runtime.h>
#include <math.h>

#define NEG_INF_F (-9000000000000000.0f)
#define SLOPE 0.01f

constexpr int B_ = 128, N_ = 10000, DIN = 64, DRAW = 64;
constexpr int CHUNK = 1024;
constexpr int NCHUNK = (N_ + CHUNK - 1) / CHUNK; // 10

// Pass 1: e[b,n] = leakyrelu(c_b + raw_x[b,n,:].a2_t); online (max,sumexp) per block chunk.
__global__ __launch_bounds__(256) void pass1_kernel(
    const float* __restrict__ x, const float* __restrict__ raw_x,
    const float* __restrict__ a, const float* __restrict__ adj,
    const int* __restrict__ node_index, const int* __restrict__ type_index,
    float* __restrict__ e_buf, float* __restrict__ pm, float* __restrict__ ps)
{
    const int b = blockIdx.y;
    const int c = blockIdx.x;
    const int tid = threadIdx.x;
    const int t = type_index[b];

    __shared__ float a2[64];
    __shared__ float s_cb;

    if (tid < 64) {
        a2[tid] = a[t * 128 + 64 + tid];
        // c_b = dot(x[b, node_index, :], a[t, 0:64]) -- wave-64 reduce
        const int ni = node_index[0];
        float v = x[((size_t)b * N_ + ni) * DIN + tid] * a[t * 128 + tid];
        for (int off = 32; off > 0; off >>= 1) v += __shfl_down(v, off);
        if (tid == 0) s_cb = v;
    }
    __syncthreads();
    const float cb = s_cb;

    float m = NEG_INF_F;
    float s = 0.f;

    const int n0 = c * CHUNK;
    const int n1 = (n0 + CHUNK < N_) ? (n0 + CHUNK) : N_;
    for (int n = n0 + tid; n < n1; n += 256) {
        if (adj[n] > 0.f) {
            const float4* row = (const float4*)(raw_x + ((size_t)b * N_ + n) * DRAW);
            float acc = 0.f;
#pragma unroll
            for (int k = 0; k < 16; ++k) {
                float4 r = row[k];
                acc += r.x * a2[4 * k + 0] + r.y * a2[4 * k + 1]
                     + r.z * a2[4 * k + 2] + r.w * a2[4 * k + 3];
            }
            float e = cb + acc;
            e = (e > 0.f) ? e : SLOPE * e;
            e_buf[(size_t)b * N_ + n] = e;
            if (e > m) { s = s * __expf(m - e) + 1.f; m = e; }
            else       { s += __expf(e - m); }
        }
    }

    // block-level (m, s) reduction
    __shared__ float sm[256];
    __shared__ float ss[256];
    sm[tid] = m; ss[tid] = s;
    __syncthreads();
    for (int off = 128; off > 0; off >>= 1) {
        if (tid < off) {
            float m2 = sm[tid + off], s2 = ss[tid + off];
            float M = fmaxf(sm[tid], m2);
            ss[tid] = ss[tid] * __expf(sm[tid] - M) + s2 * __expf(m2 - M);
            sm[tid] = M;
        }
        __syncthreads();
    }
    if (tid == 0) {
        pm[b * NCHUNK + c] = sm[0];
        ps[b * NCHUNK + c] = ss[0];
    }
}

// Pass 2: merge NCHUNK partials per b -> (M_b, 1/S_b). One wave per b.
__global__ __launch_bounds__(64) void merge_kernel(
    const float* __restrict__ pm, const float* __restrict__ ps,
    float* __restrict__ Mb, float* __restrict__ invSb)
{
    const int b = blockIdx.x;
    const int tid = threadIdx.x;
    float m = NEG_INF_F, s = 0.f;
    if (tid < NCHUNK) { m = pm[b * NCHUNK + tid]; s = ps[b * NCHUNK + tid]; }
    for (int off = 32; off > 0; off >>= 1) {
        float m2 = __shfl_down(m, off);
        float s2 = __shfl_down(s, off);
        float M = fmaxf(m, m2);
        s = s * __expf(m - M) + s2 * __expf(m2 - M);
        m = M;
    }
    if (tid == 0) { Mb[b] = m; invSb[b] = 1.f / s; }
}

// Pass 3: out[b,n] = adj[n]>0 ? exp(e - M_b) * invS_b : 0
__global__ __launch_bounds__(256) void pass3_kernel(
    const float* __restrict__ e_buf, const float* __restrict__ adj,
    const float* __restrict__ Mb, const float* __restrict__ invSb,
    float* __restrict__ out)
{
    const int b = blockIdx.y;
    const int n = blockIdx.x * 256 + threadIdx.x;
    if (n >= N_) return;
    const size_t i = (size_t)b * N_ + n;
    float o = 0.f;
    if (adj[n] > 0.f) o = __expf(e_buf[i] - Mb[b]) * invSb[b];
    out[i] = o;
}

extern "C" void kernel_launch(void* const* d_in, const int* in_sizes, int n_in,
                              void* d_out, int out_size, void* d_ws, size_t ws_size,
                              hipStream_t stream) {
    const float* x     = (const float*)d_in[0];
    const float* raw_x = (const float*)d_in[1];
    const float* a     = (const float*)d_in[2];
    const float* adj   = (const float*)d_in[3];
    const int* node_index = (const int*)d_in[4];
    const int* type_index = (const int*)d_in[5];
    float* out = (float*)d_out;

    float* e_buf = (float*)d_ws;                       // B*N
    float* pm    = e_buf + (size_t)B_ * N_;            // B*NCHUNK
    float* ps    = pm + (size_t)B_ * NCHUNK;           // B*NCHUNK
    float* Mb    = ps + (size_t)B_ * NCHUNK;           // B
    float* invSb = Mb + B_;                            // B

    dim3 g1(NCHUNK, B_);
    pass1_kernel<<<g1, 256, 0, stream>>>(x, raw_x, a, adj, node_index, type_index,
                                         e_buf, pm, ps);
    merge_kernel<<<B_, 64, 0, stream>>>(pm, ps, Mb, invSb);
    dim3 g3((N_ + 255) / 256, B_);
    pass3_kernel<<<g3, 256, 0, stream>>>(e_buf, adj, Mb, invSb, out);
}

// Round 2
// 538.630 us; speedup vs baseline: 1.0375x; 1.0375x over previous
//
#include <hip/hip_runtime.h>
#include <math.h>

#define NEG_INF_F (-9000000000000000.0f)
#define SLOPE 0.01f

constexpr int B_ = 128, N_ = 10000, DIN = 64, DRAW = 64;
constexpr int CHUNK = 1024;
constexpr int NCHUNK = (N_ + CHUNK - 1) / CHUNK; // 10

// Pass 1: e[b,n] = leakyrelu(c_b + raw_x[b,n,:].a2_t); online (max,sumexp) per chunk.
// Layout: 16 lanes per row (16 x float4 = 256B row), 4 rows per wave -> one
// contiguous 1KB global load per wave instruction (fully coalesced).
__global__ __launch_bounds__(256) void pass1_kernel(
    const float* __restrict__ x, const float* __restrict__ raw_x,
    const float* __restrict__ a, const float* __restrict__ adj,
    const int* __restrict__ node_index, const int* __restrict__ type_index,
    float* __restrict__ e_buf, float* __restrict__ pm, float* __restrict__ ps)
{
    const int b = blockIdx.y;
    const int cblk = blockIdx.x;
    const int tid = threadIdx.x;
    const int wave = tid >> 6;
    const int lane = tid & 63;
    const int r = lane >> 4;   // row within the wave's 4-row group
    const int c = lane & 15;   // 16B chunk within row
    const int t = type_index[b];

    __shared__ float s_adj[CHUNK];
    __shared__ float s_cb;

    const int n0 = cblk * CHUNK;
    const int n1 = (n0 + CHUNK < N_) ? (n0 + CHUNK) : N_;

    // preload adj chunk to LDS (OOB rows -> 0 => inactive)
    for (int i = tid; i < CHUNK; i += 256) {
        const int n = n0 + i;
        s_adj[i] = (n < N_) ? adj[n] : 0.f;
    }

    if (tid < 64) {
        const int ni = node_index[0];
        float v = x[((size_t)b * N_ + ni) * DIN + tid] * a[t * 128 + tid];
        for (int off = 32; off > 0; off >>= 1) v += __shfl_down(v, off);
        if (tid == 0) s_cb = v;
    }
    __syncthreads();
    const float cb = s_cb;

    // per-lane slice of a2: lane only ever touches a2[c*4 .. c*4+3]
    const float4 a2 = *(const float4*)(a + t * 128 + 64 + c * 4);

    float m = NEG_INF_F, s = 0.f;

    // waves stride 4 rows apart; block covers 16 consecutive rows per iter.
    // (n1-n0) is 1024 or 784, both multiples of 16 -> no row OOB inside loop.
    for (int base = n0 + wave * 4; base < n1; base += 16) {
        const int row = base + r;
        const bool act = s_adj[base - n0 + r] > 0.f;  // uniform across the 16-lane group
        if (act) {
            const float4 rv = *(const float4*)(raw_x + ((size_t)b * N_ + base) * DRAW + lane * 4);
            float acc = rv.x * a2.x + rv.y * a2.y + rv.z * a2.z + rv.w * a2.w;
            acc += __shfl_xor(acc, 1);
            acc += __shfl_xor(acc, 2);
            acc += __shfl_xor(acc, 4);
            acc += __shfl_xor(acc, 8);   // all 16 lanes of group now hold full dot
            float e = cb + acc;
            e = (e > 0.f) ? e : SLOPE * e;
            // all 16 lanes accumulate identically; divide s by 16 at the end
            const float M = fmaxf(m, e);
            s = s * __expf(m - M) + __expf(e - M);
            m = M;
            if (c == 0) e_buf[(size_t)b * N_ + row] = e;
        }
    }

    // block-level (m, s) reduction
    __shared__ float sm[256];
    __shared__ float ss[256];
    sm[tid] = m; ss[tid] = s;
    __syncthreads();
    for (int off = 128; off > 0; off >>= 1) {
        if (tid < off) {
            const float m2 = sm[tid + off], s2 = ss[tid + off];
            const float M = fmaxf(sm[tid], m2);
            ss[tid] = ss[tid] * __expf(sm[tid] - M) + s2 * __expf(m2 - M);
            sm[tid] = M;
        }
        __syncthreads();
    }
    if (tid == 0) {
        pm[b * NCHUNK + cblk] = sm[0];
        ps[b * NCHUNK + cblk] = ss[0] * (1.f / 16.f);  // undo 16x redundant accumulation
    }
}

// Pass 2 (merge folded in): out[b,n] = adj[n]>0 ? exp(e - M_b) * invS_b : 0
__global__ __launch_bounds__(256) void pass3_kernel(
    const float* __restrict__ e_buf, const float* __restrict__ adj,
    const float* __restrict__ pm, const float* __restrict__ ps,
    float* __restrict__ out)
{
    const int b = blockIdx.y;
    const int tid = threadIdx.x;

    __shared__ float sM, sInv;
    if (tid == 0) {
        float m = NEG_INF_F, s = 0.f;
        for (int i = 0; i < NCHUNK; ++i) {
            const float m2 = pm[b * NCHUNK + i], s2 = ps[b * NCHUNK + i];
            const float M = fmaxf(m, m2);
            s = s * __expf(m - M) + s2 * __expf(m2 - M);
            m = M;
        }
        sM = m; sInv = 1.f / s;
    }
    __syncthreads();
    const float M = sM, inv = sInv;

    const int idx4 = blockIdx.x * 256 + tid;           // float4 index
    if (idx4 >= N_ / 4) return;                         // N_ = 10000 -> 2500 float4s
    const float4 a4 = ((const float4*)adj)[idx4];
    const float4 e4 = ((const float4*)(e_buf + (size_t)b * N_))[idx4];
    float4 o;
    o.x = (a4.x > 0.f) ? __expf(e4.x - M) * inv : 0.f;
    o.y = (a4.y > 0.f) ? __expf(e4.y - M) * inv : 0.f;
    o.z = (a4.z > 0.f) ? __expf(e4.z - M) * inv : 0.f;
    o.w = (a4.w > 0.f) ? __expf(e4.w - M) * inv : 0.f;
    ((float4*)(out + (size_t)b * N_))[idx4] = o;
}

extern "C" void kernel_launch(void* const* d_in, const int* in_sizes, int n_in,
                              void* d_out, int out_size, void* d_ws, size_t ws_size,
                              hipStream_t stream) {
    const float* x     = (const float*)d_in[0];
    const float* raw_x = (const float*)d_in[1];
    const float* a     = (const float*)d_in[2];
    const float* adj   = (const float*)d_in[3];
    const int* node_index = (const int*)d_in[4];
    const int* type_index = (const int*)d_in[5];
    float* out = (float*)d_out;

    float* e_buf = (float*)d_ws;                       // B*N
    float* pm    = e_buf + (size_t)B_ * N_;            // B*NCHUNK
    float* ps    = pm + (size_t)B_ * NCHUNK;           // B*NCHUNK

    dim3 g1(NCHUNK, B_);
    pass1_kernel<<<g1, 256, 0, stream>>>(x, raw_x, a, adj, node_index, type_index,
                                         e_buf, pm, ps);
    dim3 g3((N_ / 4 + 255) / 256, B_);
    pass3_kernel<<<g3, 256, 0, stream>>>(e_buf, adj, pm, ps, out);
}

// Round 3
// 534.639 us; speedup vs baseline: 1.0453x; 1.0075x over previous
//
#include <hip/hip_runtime.h>
#include <math.h>

#define NEG_INF_F (-9000000000000000.0f)
#define SLOPE 0.01f

constexpr int B_ = 128, N_ = 10000, DIN = 64, DRAW = 64;
constexpr int CHUNK = 1024;
constexpr int NCHUNK = (N_ + CHUNK - 1) / CHUNK; // 10

// Pass 1: e[b,n] = leakyrelu(c_b + raw_x[b,n,:].a2_t); online (max,sumexp) per chunk.
// Layout: 16 lanes per row (16 x float4 = 256B row), 4 rows per wave-load -> one
// contiguous 1KB global load per wave instruction. 2x unrolled: two independent
// 1KB loads in flight per wave per iteration for latency hiding.
__global__ __launch_bounds__(256) void pass1_kernel(
    const float* __restrict__ x, const float* __restrict__ raw_x,
    const float* __restrict__ a, const float* __restrict__ adj,
    const int* __restrict__ node_index, const int* __restrict__ type_index,
    float* __restrict__ e_buf, float* __restrict__ pm, float* __restrict__ ps)
{
    const int b = blockIdx.y;
    const int cblk = blockIdx.x;
    const int tid = threadIdx.x;
    const int wave = tid >> 6;
    const int lane = tid & 63;
    const int r = lane >> 4;   // row within a 4-row load group
    const int c = lane & 15;   // 16B chunk within row
    const int t = type_index[b];

    __shared__ float s_adj[CHUNK];
    __shared__ float s_cb;

    const int n0 = cblk * CHUNK;
    const int n1 = (n0 + CHUNK < N_) ? (n0 + CHUNK) : N_;

    for (int i = tid; i < CHUNK; i += 256) {
        const int n = n0 + i;
        s_adj[i] = (n < N_) ? adj[n] : 0.f;
    }

    if (tid < 64) {
        const int ni = node_index[0];
        float v = x[((size_t)b * N_ + ni) * DIN + tid] * a[t * 128 + tid];
        for (int off = 32; off > 0; off >>= 1) v += __shfl_down(v, off);
        if (tid == 0) s_cb = v;
    }
    __syncthreads();
    const float cb = s_cb;

    // per-lane slice of a2: lane only ever touches a2[c*4 .. c*4+3]
    const float4 a2 = *(const float4*)(a + t * 128 + 64 + c * 4);

    float m = NEG_INF_F, s = 0.f;

    const float* rxb = raw_x + (size_t)b * N_ * DRAW;

    // waves stride 8 rows; block covers 32 rows/iter. n1-n0 is 1024 or 784
    // (both multiples of 16, and of 4), so the base+4 guard below suffices.
    for (int base = n0 + wave * 8; base < n1; base += 32) {
        const bool has1 = (base + 4) < n1;
        const bool act0 = s_adj[base - n0 + r] > 0.f;                 // uniform per 16-lane group
        const bool act1 = has1 && (s_adj[base + 4 - n0 + r] > 0.f);

        float4 v0, v1;
        if (act0) v0 = *(const float4*)(rxb + (size_t)base * DRAW + lane * 4);
        if (act1) v1 = *(const float4*)(rxb + (size_t)(base + 4) * DRAW + lane * 4);

        if (act0) {
            float acc = v0.x * a2.x + v0.y * a2.y + v0.z * a2.z + v0.w * a2.w;
            acc += __shfl_xor(acc, 1);
            acc += __shfl_xor(acc, 2);
            acc += __shfl_xor(acc, 4);
            acc += __shfl_xor(acc, 8);
            float e = cb + acc;
            e = (e > 0.f) ? e : SLOPE * e;
            const float M = fmaxf(m, e);
            s = s * __expf(m - M) + __expf(e - M);
            m = M;
            if (c == 0) e_buf[(size_t)b * N_ + base + r] = e;
        }
        if (act1) {
            float acc = v1.x * a2.x + v1.y * a2.y + v1.z * a2.z + v1.w * a2.w;
            acc += __shfl_xor(acc, 1);
            acc += __shfl_xor(acc, 2);
            acc += __shfl_xor(acc, 4);
            acc += __shfl_xor(acc, 8);
            float e = cb + acc;
            e = (e > 0.f) ? e : SLOPE * e;
            const float M = fmaxf(m, e);
            s = s * __expf(m - M) + __expf(e - M);
            m = M;
            if (c == 0) e_buf[(size_t)b * N_ + base + 4 + r] = e;
        }
    }

    // block-level (m, s) reduction; every lane counted each of its group's rows
    // once -> 16x redundancy, divided out below.
    __shared__ float sm[256];
    __shared__ float ss[256];
    sm[tid] = m; ss[tid] = s;
    __syncthreads();
    for (int off = 128; off > 0; off >>= 1) {
        if (tid < off) {
            const float m2 = sm[tid + off], s2 = ss[tid + off];
            const float M = fmaxf(sm[tid], m2);
            ss[tid] = ss[tid] * __expf(sm[tid] - M) + s2 * __expf(m2 - M);
            sm[tid] = M;
        }
        __syncthreads();
    }
    if (tid == 0) {
        pm[b * NCHUNK + cblk] = sm[0];
        ps[b * NCHUNK + cblk] = ss[0] * (1.f / 16.f);
    }
}

// Pass 2: merge partials (16-lane parallel) + normalize + write.
__global__ __launch_bounds__(256) void pass3_kernel(
    const float* __restrict__ e_buf, const float* __restrict__ adj,
    const float* __restrict__ pm, const float* __restrict__ ps,
    float* __restrict__ out)
{
    const int b = blockIdx.y;
    const int tid = threadIdx.x;

    __shared__ float sM, sInv;
    if (tid < 16) {
        float m = NEG_INF_F, s = 0.f;
        if (tid < NCHUNK) { m = pm[b * NCHUNK + tid]; s = ps[b * NCHUNK + tid]; }
        for (int off = 8; off > 0; off >>= 1) {
            const float m2 = __shfl_xor(m, off);
            const float s2 = __shfl_xor(s, off);
            const float M = fmaxf(m, m2);
            s = s * __expf(m - M) + s2 * __expf(m2 - M);
            m = M;
        }
        if (tid == 0) { sM = m; sInv = 1.f / s; }
    }
    __syncthreads();
    const float M = sM, inv = sInv;

    const int idx4 = blockIdx.x * 256 + tid;            // float4 index
    if (idx4 >= N_ / 4) return;                          // N_=10000 -> 2500 float4s
    const float4 a4 = ((const float4*)adj)[idx4];
    const float4 e4 = ((const float4*)(e_buf + (size_t)b * N_))[idx4];
    float4 o;
    o.x = (a4.x > 0.f) ? __expf(e4.x - M) * inv : 0.f;
    o.y = (a4.y > 0.f) ? __expf(e4.y - M) * inv : 0.f;
    o.z = (a4.z > 0.f) ? __expf(e4.z - M) * inv : 0.f;
    o.w = (a4.w > 0.f) ? __expf(e4.w - M) * inv : 0.f;
    ((float4*)(out + (size_t)b * N_))[idx4] = o;
}

extern "C" void kernel_launch(void* const* d_in, const int* in_sizes, int n_in,
                              void* d_out, int out_size, void* d_ws, size_t ws_size,
                              hipStream_t stream) {
    const float* x     = (const float*)d_in[0];
    const float* raw_x = (const float*)d_in[1];
    const float* a     = (const float*)d_in[2];
    const float* adj   = (const float*)d_in[3];
    const int* node_index = (const int*)d_in[4];
    const int* type_index = (const int*)d_in[5];
    float* out = (float*)d_out;

    float* e_buf = (float*)d_ws;                       // B*N
    float* pm    = e_buf + (size_t)B_ * N_;            // B*NCHUNK
    float* ps    = pm + (size_t)B_ * NCHUNK;           // B*NCHUNK

    dim3 g1(NCHUNK, B_);
    pass1_kernel<<<g1, 256, 0, stream>>>(x, raw_x, a, adj, node_index, type_index,
                                         e_buf, pm, ps);
    dim3 g3((N_ / 4 + 255) / 256, B_);
    pass3_kernel<<<g3, 256, 0, stream>>>(e_buf, adj, pm, ps, out);
}